// Round 2
// baseline (2155.552 us; speedup 1.0000x reference)
//
#include <hip/hip_runtime.h>
#include <hip/hip_bf16.h>

#define NN 50000
#define EE 800000
#define TT 4

typedef __hip_bfloat16 bf16;
typedef short bf16x8 __attribute__((ext_vector_type(8)));
typedef float f32x4 __attribute__((ext_vector_type(4)));

// ---------------- prep: build W_allT [512][768] bf16, fused bias[512] fp32,
// and Wpool bf16 copy ----------------
// G = Z @ W_all, Z cols: [Xp, P Xp, T2 Xp, H, P H, T2 H] (6*128)
// W_allT[n][k], n = g*128 + c_out (g: i,f,c,o), k = xh*384 + kch*128 + r
// value = conv_W[2g+xh][kch][r][c_out]
__global__ void prep_kernel(const float* __restrict__ convW, const float* __restrict__ convB,
                            const float* __restrict__ gateB, const float* __restrict__ Wpool,
                            bf16* __restrict__ WallT, float* __restrict__ bias,
                            bf16* __restrict__ WpoolBf) {
  int idx = blockIdx.x * 256 + threadIdx.x;
  if (idx < 512 * 768) {
    int nn = idx / 768, k = idx % 768;
    int g = nn >> 7, c = nn & 127;
    int xh = (k >= 384) ? 1 : 0;
    int k2 = k - xh * 384;
    int kch = k2 >> 7, r = k2 & 127;
    WallT[idx] = __float2bfloat16(convW[(((2 * g + xh) * 3 + kch) * 128 + r) * 128 + c]);
  } else if (idx < 512 * 768 + 512) {
    int n2 = idx - 512 * 768;
    int g = n2 >> 7, c = n2 & 127;
    bias[n2] = convB[(2 * g) * 128 + c] + convB[(2 * g + 1) * 128 + c] + gateB[g * 128 + c];
  } else if (idx < 512 * 768 + 512 + 128 * 128) {
    int n3 = idx - (512 * 768 + 512);
    WpoolBf[n3] = __float2bfloat16(Wpool[n3]);
  }
}

// ---------------- graph preprocessing ----------------
__global__ void degcount_kernel(const int* __restrict__ src, const int* __restrict__ dst,
                                float* __restrict__ deg, int* __restrict__ counts) {
  int e = blockIdx.x * 256 + threadIdx.x;
  if (e < EE) {
    atomicAdd(&deg[src[e]], 1.0f);
    atomicAdd(&counts[dst[e]], 1);
  }
}

__global__ void dinv_kernel(float* deg) {
  int n = blockIdx.x * 256 + threadIdx.x;
  if (n < NN) {
    float d = deg[n];
    deg[n] = (d > 0.f) ? rsqrtf(d) : 0.f;
  }
}

__global__ void scan_kernel(const int* __restrict__ counts, int* __restrict__ row_ptr,
                            int* __restrict__ cursor) {
  __shared__ int lds[1024];
  __shared__ int carry_s;
  int tid = threadIdx.x;
  if (tid == 0) carry_s = 0;
  __syncthreads();
  for (int base = 0; base < NN; base += 1024) {
    int i = base + tid;
    int v = (i < NN) ? counts[i] : 0;
    lds[tid] = v;
    __syncthreads();
    for (int off = 1; off < 1024; off <<= 1) {
      int t = (tid >= off) ? lds[tid - off] : 0;
      __syncthreads();
      lds[tid] += t;
      __syncthreads();
    }
    int carry = carry_s;
    int excl = lds[tid] - v + carry;
    if (i < NN) { row_ptr[i] = excl; cursor[i] = excl; }
    __syncthreads();
    if (tid == 0) carry_s = carry + lds[1023];
    __syncthreads();
  }
  if (tid == 0) row_ptr[NN] = carry_s;
}

__global__ void fill_kernel(const int* __restrict__ src, const int* __restrict__ dst,
                            const float* __restrict__ dinv, int* __restrict__ cursor,
                            int* __restrict__ ssrc, float* __restrict__ sw) {
  int e = blockIdx.x * 256 + threadIdx.x;
  if (e < EE) {
    int s = src[e], d = dst[e];
    float w = -(dinv[s] * dinv[d]);
    int pos = atomicAdd(&cursor[d], 1);
    ssrc[pos] = s;
    sw[pos] = w;
  }
}

// ---------------- prop: out = scale * (P @ in) - base (per node CSR gather) ----------------
// two column-pairs per block: threads 0-127 pair A, 128-255 pair B
__global__ void prop_dual(const int* __restrict__ row_ptr, const int* __restrict__ ssrc,
                          const float* __restrict__ sw, bf16* __restrict__ Z,
                          int in_offA, int out_offA, int baseA,
                          int in_offB, int out_offB, int baseB, float scale) {
  int n = blockIdx.x;
  int tid = threadIdx.x;
  int c = tid & 127;
  int grp = tid >> 7;
  int in_off  = grp ? in_offB  : in_offA;
  int out_off = grp ? out_offB : out_offA;
  int base    = grp ? baseB    : baseA;
  int e0 = row_ptr[n], e1 = row_ptr[n + 1];
  float acc = 0.f;
  const bf16* zin = Z + in_off + c;
  for (int e = e0; e < e1; ++e) {
    acc += sw[e] * __bfloat162float(zin[(size_t)ssrc[e] * 768]);
  }
  float r = scale * acc;
  if (base >= 0) r -= __bfloat162float(Z[(size_t)n * 768 + base + c]);
  Z[(size_t)n * 768 + out_off + c] = __float2bfloat16(r);
}

// ---------------- GEMM: C[M,Nc] = A[M,K] @ Bt[Nc,K]^T, fp32 acc ----------------
// A is fp32 (converted during staging) if A_FP32, else bf16. Bt is bf16.
// 128x128 block tile, 256 threads (2x2 waves of 64x64), 16x16x32 bf16 MFMA, BK=32.
template <int A_FP32>
__global__ __launch_bounds__(256) void gemm_bt(const void* __restrict__ Ain, int lda,
                                               const bf16* __restrict__ Bt, int ldbt,
                                               bf16* __restrict__ Cout, int ldc,
                                               int M, int K) {
  __shared__ __align__(16) bf16 As[128 * 40];  // row stride 40 bf16 (80B): no conflicts
  __shared__ __align__(16) bf16 Bs[128 * 40];
  const int tid = threadIdx.x;
  const int lane = tid & 63, wid = tid >> 6;
  const int wm = wid >> 1, wn = wid & 1;
  const int m_base = blockIdx.x * 128;
  const int n_base = blockIdx.y * 128;
  f32x4 acc[4][4] = {};

  for (int k0 = 0; k0 < K; k0 += 32) {
#pragma unroll
    for (int it = 0; it < 2; ++it) {
      int cc = tid + it * 256;          // 512 chunks of 8 bf16 per tile
      int row = cc >> 2, seg = cc & 3;
      int ar = m_base + row;
      if (A_FP32) {
        float4 f0 = make_float4(0.f, 0.f, 0.f, 0.f), f1 = f0;
        if (ar < M) {
          const float* ap = (const float*)Ain + (size_t)ar * lda + k0 + seg * 8;
          f0 = *(const float4*)ap;
          f1 = *(const float4*)(ap + 4);
        }
        bf16 tmp[8];
        tmp[0] = __float2bfloat16(f0.x); tmp[1] = __float2bfloat16(f0.y);
        tmp[2] = __float2bfloat16(f0.z); tmp[3] = __float2bfloat16(f0.w);
        tmp[4] = __float2bfloat16(f1.x); tmp[5] = __float2bfloat16(f1.y);
        tmp[6] = __float2bfloat16(f1.z); tmp[7] = __float2bfloat16(f1.w);
        *(uint4*)(As + row * 40 + seg * 8) = *(const uint4*)tmp;
      } else {
        uint4 va = make_uint4(0u, 0u, 0u, 0u);
        if (ar < M) va = *(const uint4*)((const bf16*)Ain + (size_t)ar * lda + k0 + seg * 8);
        *(uint4*)(As + row * 40 + seg * 8) = va;
      }
      uint4 vb = *(const uint4*)(Bt + (size_t)(n_base + row) * ldbt + k0 + seg * 8);
      *(uint4*)(Bs + row * 40 + seg * 8) = vb;
    }
    __syncthreads();
    bf16x8 af[4], bfr[4];
#pragma unroll
    for (int tm = 0; tm < 4; ++tm) {
      int r = wm * 64 + tm * 16 + (lane & 15);
      af[tm] = *(const bf16x8*)(As + r * 40 + (lane >> 4) * 8);
    }
#pragma unroll
    for (int tn = 0; tn < 4; ++tn) {
      int r = wn * 64 + tn * 16 + (lane & 15);
      bfr[tn] = *(const bf16x8*)(Bs + r * 40 + (lane >> 4) * 8);
    }
#pragma unroll
    for (int tm = 0; tm < 4; ++tm)
#pragma unroll
      for (int tn = 0; tn < 4; ++tn)
        acc[tm][tn] = __builtin_amdgcn_mfma_f32_16x16x32_bf16(af[tm], bfr[tn], acc[tm][tn], 0, 0, 0);
    __syncthreads();
  }

  // C/D layout: col = lane&15, row = (lane>>4)*4 + i  [m89/m91 verified]
#pragma unroll
  for (int tm = 0; tm < 4; ++tm) {
#pragma unroll
    for (int tn = 0; tn < 4; ++tn) {
      int col = n_base + wn * 64 + tn * 16 + (lane & 15);
#pragma unroll
      for (int i = 0; i < 4; ++i) {
        int row = m_base + wm * 64 + tm * 16 + (lane >> 4) * 4 + i;
        if (row < M)
          Cout[(size_t)row * ldc + col] = __float2bfloat16(acc[tm][tn][i]);
      }
    }
  }
}

// ---------------- LSTM pointwise ----------------
__global__ void lstm_kernel(const bf16* __restrict__ G, float* __restrict__ Cst,
                            bf16* __restrict__ Z, float* __restrict__ out,
                            const float* __restrict__ bias, const float* __restrict__ peep,
                            int t) {
  int idx = blockIdx.x * 256 + threadIdx.x;  // n*128 + c
  int n = idx >> 7, c = idx & 127;
  const bf16* g = G + (size_t)n * 512;
  float Cold = Cst[idx];
  float ai = __bfloat162float(g[c])       + bias[c]       + peep[c] * Cold;
  float af = __bfloat162float(g[128 + c]) + bias[128 + c] + peep[128 + c] * Cold;
  float ac = __bfloat162float(g[256 + c]) + bias[256 + c];
  float ao = __bfloat162float(g[384 + c]) + bias[384 + c];
  float I = 1.f / (1.f + expf(-ai));
  float F = 1.f / (1.f + expf(-af));
  float Tc = tanhf(ac);
  float Cn = F * Cold + I * Tc;
  float O = 1.f / (1.f + expf(-(ao + peep[256 + c] * Cn)));
  float H = O * tanhf(Cn);
  Cst[idx] = Cn;
  Z[(size_t)n * 768 + 384 + c] = __float2bfloat16(H);
  out[((size_t)n * 4 + t) * 128 + c] = H;
}

extern "C" void kernel_launch(void* const* d_in, const int* in_sizes, int n_in,
                              void* d_out, int out_size, void* d_ws, size_t ws_size,
                              hipStream_t stream) {
  const float* X     = (const float*)d_in[0];
  const int*   edges = (const int*)d_in[1];
  const float* Wpool = (const float*)d_in[2];
  const float* convW = (const float*)d_in[3];
  const float* convB = (const float*)d_in[4];
  const float* peep  = (const float*)d_in[5];
  const float* gateB = (const float*)d_in[6];
  float* out = (float*)d_out;

  const int* src = edges;
  const int* dst = edges + EE;

  char* ws = (char*)d_ws;
  size_t off = 0;
  auto alloc = [&](size_t bytes) {
    void* p = ws + off;
    off += (bytes + 255) & ~(size_t)255;
    return p;
  };
  bf16*  WallT   = (bf16*) alloc((size_t)512 * 768 * 2);
  bf16*  WpoolBf = (bf16*) alloc((size_t)128 * 128 * 2);
  float* bias    = (float*)alloc(512 * 4);
  float* dinv    = (float*)alloc(NN * 4);       // also used as deg accumulator
  int*   counts  = (int*)  alloc(NN * 4);
  int*   rowp    = (int*)  alloc((NN + 1) * 4);
  int*   cursor  = (int*)  alloc(NN * 4);
  int*   ssrc    = (int*)  alloc((size_t)EE * 4);
  float* sw      = (float*)alloc((size_t)EE * 4);
  float* Cst     = (float*)alloc((size_t)NN * 128 * 4);
  bf16*  Z       = (bf16*) alloc((size_t)NN * 768 * 2);
  bf16*  G       = (bf16*) alloc((size_t)NN * 512 * 2);

  hipMemsetAsync(dinv, 0, NN * 4, stream);
  hipMemsetAsync(counts, 0, NN * 4, stream);
  hipMemsetAsync(Cst, 0, (size_t)NN * 128 * 4, stream);
  hipMemsetAsync(Z, 0, (size_t)NN * 768 * 2, stream);

  prep_kernel<<<1667, 256, 0, stream>>>(convW, convB, gateB, Wpool, WallT, bias, WpoolBf);
  degcount_kernel<<<(EE + 255) / 256, 256, 0, stream>>>(src, dst, dinv, counts);
  dinv_kernel<<<(NN + 255) / 256, 256, 0, stream>>>(dinv);
  scan_kernel<<<1, 1024, 0, stream>>>(counts, rowp, cursor);
  fill_kernel<<<(EE + 255) / 256, 256, 0, stream>>>(src, dst, dinv, cursor, ssrc, sw);

  dim3 blk(256);
  for (int t = 0; t < TT; ++t) {
    // Xp = X_t @ Wpool^T -> Z[:,0:128]  (Wpool [C][F] is already Bt layout)
    gemm_bt<1><<<dim3(391, 1), blk, 0, stream>>>(X + (size_t)t * NN * 128, 128,
                                                 WpoolBf, 128, Z, 768, NN, 128);
    // PXp (0->128), PH (384->512)
    prop_dual<<<NN, blk, 0, stream>>>(rowp, ssrc, sw, Z, 0, 128, -1, 384, 512, -1, 1.0f);
    // T2Xp = 2*P*PXp - Xp (128->256, base 0); T2H = 2*P*PH - H (512->640, base 384)
    prop_dual<<<NN, blk, 0, stream>>>(rowp, ssrc, sw, Z, 128, 256, 0, 512, 640, 384, 2.0f);
    // G[N,512] = Z[N,768] @ W_all
    gemm_bt<0><<<dim3(391, 4), blk, 0, stream>>>(Z, 768, WallT, 768, G, 512, NN, 768);
    // gates + cell update + output
    lstm_kernel<<<(NN * 128) / 256, blk, 0, stream>>>(G, Cst, Z, out, bias, peep, t);
  }
}

// Round 3
// 1368.799 us; speedup vs baseline: 1.5748x; 1.5748x over previous
//
#include <hip/hip_runtime.h>
#include <hip/hip_bf16.h>

#define NN 50000
#define EE 800000
#define TT 4

typedef __hip_bfloat16 bf16;
typedef short bf16x8 __attribute__((ext_vector_type(8)));
typedef float f32x4 __attribute__((ext_vector_type(4)));

// ---------------- prep: build W_allT [512][768] bf16, fused bias[512] fp32,
// and Wpool bf16 copy ----------------
__global__ void prep_kernel(const float* __restrict__ convW, const float* __restrict__ convB,
                            const float* __restrict__ gateB, const float* __restrict__ Wpool,
                            bf16* __restrict__ WallT, float* __restrict__ bias,
                            bf16* __restrict__ WpoolBf) {
  int idx = blockIdx.x * 256 + threadIdx.x;
  if (idx < 512 * 768) {
    int nn = idx / 768, k = idx % 768;
    int g = nn >> 7, c = nn & 127;
    int xh = (k >= 384) ? 1 : 0;
    int k2 = k - xh * 384;
    int kch = k2 >> 7, r = k2 & 127;
    WallT[idx] = __float2bfloat16(convW[(((2 * g + xh) * 3 + kch) * 128 + r) * 128 + c]);
  } else if (idx < 512 * 768 + 512) {
    int n2 = idx - 512 * 768;
    int g = n2 >> 7, c = n2 & 127;
    bias[n2] = convB[(2 * g) * 128 + c] + convB[(2 * g + 1) * 128 + c] + gateB[g * 128 + c];
  } else if (idx < 512 * 768 + 512 + 128 * 128) {
    int n3 = idx - (512 * 768 + 512);
    WpoolBf[n3] = __float2bfloat16(Wpool[n3]);
  }
}

// ---------------- graph preprocessing ----------------
__global__ void degcount_kernel(const int* __restrict__ src, const int* __restrict__ dst,
                                float* __restrict__ deg, int* __restrict__ counts) {
  int e = blockIdx.x * 256 + threadIdx.x;
  if (e < EE) {
    atomicAdd(&deg[src[e]], 1.0f);
    atomicAdd(&counts[dst[e]], 1);
  }
}

__global__ void dinv_kernel(float* deg) {
  int n = blockIdx.x * 256 + threadIdx.x;
  if (n < NN) {
    float d = deg[n];
    deg[n] = (d > 0.f) ? rsqrtf(d) : 0.f;
  }
}

__global__ void scan_kernel(const int* __restrict__ counts, int* __restrict__ row_ptr,
                            int* __restrict__ cursor) {
  __shared__ int lds[1024];
  __shared__ int carry_s;
  int tid = threadIdx.x;
  if (tid == 0) carry_s = 0;
  __syncthreads();
  for (int base = 0; base < NN; base += 1024) {
    int i = base + tid;
    int v = (i < NN) ? counts[i] : 0;
    lds[tid] = v;
    __syncthreads();
    for (int off = 1; off < 1024; off <<= 1) {
      int t = (tid >= off) ? lds[tid - off] : 0;
      __syncthreads();
      lds[tid] += t;
      __syncthreads();
    }
    int carry = carry_s;
    int excl = lds[tid] - v + carry;
    if (i < NN) { row_ptr[i] = excl; cursor[i] = excl; }
    __syncthreads();
    if (tid == 0) carry_s = carry + lds[1023];
    __syncthreads();
  }
  if (tid == 0) row_ptr[NN] = carry_s;
}

// pack (src, weight) per edge into uint2
__global__ void fill_kernel(const int* __restrict__ src, const int* __restrict__ dst,
                            const float* __restrict__ dinv, int* __restrict__ cursor,
                            uint2* __restrict__ edata) {
  int e = blockIdx.x * 256 + threadIdx.x;
  if (e < EE) {
    int s = src[e], d = dst[e];
    float w = -(dinv[s] * dinv[d]);
    int pos = atomicAdd(&cursor[d], 1);
    uint2 v;
    v.x = (unsigned)s;
    v.y = __float_as_uint(w);
    edata[pos] = v;
  }
}

// ---------------- prop: out = scale * (P @ in) - base ----------------
// Block = 256 threads = 2 pairs x 8 nodes x 16 lanes. Each lane owns 8 channels
// (one uint4 = 8 bf16 per gather). 4-deep manual unroll keeps 4 gathers in flight.
__device__ __forceinline__ void accum8(float* acc, uint4 z, float w) {
  float f0 = __uint_as_float(z.x << 16);
  float f1 = __uint_as_float(z.x & 0xffff0000u);
  float f2 = __uint_as_float(z.y << 16);
  float f3 = __uint_as_float(z.y & 0xffff0000u);
  float f4 = __uint_as_float(z.z << 16);
  float f5 = __uint_as_float(z.z & 0xffff0000u);
  float f6 = __uint_as_float(z.w << 16);
  float f7 = __uint_as_float(z.w & 0xffff0000u);
  acc[0] = fmaf(w, f0, acc[0]);
  acc[1] = fmaf(w, f1, acc[1]);
  acc[2] = fmaf(w, f2, acc[2]);
  acc[3] = fmaf(w, f3, acc[3]);
  acc[4] = fmaf(w, f4, acc[4]);
  acc[5] = fmaf(w, f5, acc[5]);
  acc[6] = fmaf(w, f6, acc[6]);
  acc[7] = fmaf(w, f7, acc[7]);
}

__global__ __launch_bounds__(256) void prop_wide(const int* __restrict__ row_ptr,
                                                 const uint2* __restrict__ edata,
                                                 bf16* __restrict__ Z,
                                                 int in_offA, int out_offA, int baseA,
                                                 int in_offB, int out_offB, int baseB,
                                                 float scale) {
  int tid = threadIdx.x;
  int grp = tid >> 7;
  int sub = tid & 127;
  int node = blockIdx.x * 8 + (sub >> 4);
  int lane8 = sub & 15;
  int in_off  = grp ? in_offB  : in_offA;
  int out_off = grp ? out_offB : out_offA;
  int base    = grp ? baseB    : baseA;
  int e0 = row_ptr[node], e1 = row_ptr[node + 1];
  float acc[8] = {0.f, 0.f, 0.f, 0.f, 0.f, 0.f, 0.f, 0.f};
  const bf16* zin = Z + in_off + lane8 * 8;
  int e = e0;
  for (; e + 4 <= e1; e += 4) {
    uint2 d0 = edata[e];
    uint2 d1 = edata[e + 1];
    uint2 d2 = edata[e + 2];
    uint2 d3 = edata[e + 3];
    uint4 z0 = *(const uint4*)(zin + (size_t)d0.x * 768);
    uint4 z1 = *(const uint4*)(zin + (size_t)d1.x * 768);
    uint4 z2 = *(const uint4*)(zin + (size_t)d2.x * 768);
    uint4 z3 = *(const uint4*)(zin + (size_t)d3.x * 768);
    accum8(acc, z0, __uint_as_float(d0.y));
    accum8(acc, z1, __uint_as_float(d1.y));
    accum8(acc, z2, __uint_as_float(d2.y));
    accum8(acc, z3, __uint_as_float(d3.y));
  }
  for (; e < e1; ++e) {
    uint2 d = edata[e];
    uint4 z = *(const uint4*)(zin + (size_t)d.x * 768);
    accum8(acc, z, __uint_as_float(d.y));
  }
  float bv[8] = {0.f, 0.f, 0.f, 0.f, 0.f, 0.f, 0.f, 0.f};
  if (base >= 0) {
    uint4 b = *(const uint4*)(Z + (size_t)node * 768 + base + lane8 * 8);
    bv[0] = __uint_as_float(b.x << 16);
    bv[1] = __uint_as_float(b.x & 0xffff0000u);
    bv[2] = __uint_as_float(b.y << 16);
    bv[3] = __uint_as_float(b.y & 0xffff0000u);
    bv[4] = __uint_as_float(b.z << 16);
    bv[5] = __uint_as_float(b.z & 0xffff0000u);
    bv[6] = __uint_as_float(b.w << 16);
    bv[7] = __uint_as_float(b.w & 0xffff0000u);
  }
  union {
    bf16 h[8];
    uint4 v;
  } o;
#pragma unroll
  for (int j = 0; j < 8; ++j)
    o.h[j] = __float2bfloat16(fmaf(scale, acc[j], -bv[j]));
  *(uint4*)(Z + (size_t)node * 768 + out_off + lane8 * 8) = o.v;
}

// ---------------- GEMM: C[M,Nc] = A[M,K] @ Bt[Nc,K]^T, fp32 acc ----------------
template <int A_FP32>
__global__ __launch_bounds__(256) void gemm_bt(const void* __restrict__ Ain, int lda,
                                               const bf16* __restrict__ Bt, int ldbt,
                                               bf16* __restrict__ Cout, int ldc,
                                               int M, int K) {
  __shared__ __align__(16) bf16 As[128 * 40];  // row stride 40 bf16 (80B): no conflicts
  __shared__ __align__(16) bf16 Bs[128 * 40];
  const int tid = threadIdx.x;
  const int lane = tid & 63, wid = tid >> 6;
  const int wm = wid >> 1, wn = wid & 1;
  const int m_base = blockIdx.x * 128;
  const int n_base = blockIdx.y * 128;
  f32x4 acc[4][4] = {};

  for (int k0 = 0; k0 < K; k0 += 32) {
#pragma unroll
    for (int it = 0; it < 2; ++it) {
      int cc = tid + it * 256;
      int row = cc >> 2, seg = cc & 3;
      int ar = m_base + row;
      if (A_FP32) {
        float4 f0 = make_float4(0.f, 0.f, 0.f, 0.f), f1 = f0;
        if (ar < M) {
          const float* ap = (const float*)Ain + (size_t)ar * lda + k0 + seg * 8;
          f0 = *(const float4*)ap;
          f1 = *(const float4*)(ap + 4);
        }
        bf16 tmp[8];
        tmp[0] = __float2bfloat16(f0.x); tmp[1] = __float2bfloat16(f0.y);
        tmp[2] = __float2bfloat16(f0.z); tmp[3] = __float2bfloat16(f0.w);
        tmp[4] = __float2bfloat16(f1.x); tmp[5] = __float2bfloat16(f1.y);
        tmp[6] = __float2bfloat16(f1.z); tmp[7] = __float2bfloat16(f1.w);
        *(uint4*)(As + row * 40 + seg * 8) = *(const uint4*)tmp;
      } else {
        uint4 va = make_uint4(0u, 0u, 0u, 0u);
        if (ar < M) va = *(const uint4*)((const bf16*)Ain + (size_t)ar * lda + k0 + seg * 8);
        *(uint4*)(As + row * 40 + seg * 8) = va;
      }
      uint4 vb = *(const uint4*)(Bt + (size_t)(n_base + row) * ldbt + k0 + seg * 8);
      *(uint4*)(Bs + row * 40 + seg * 8) = vb;
    }
    __syncthreads();
    bf16x8 af[4], bfr[4];
#pragma unroll
    for (int tm = 0; tm < 4; ++tm) {
      int r = wm * 64 + tm * 16 + (lane & 15);
      af[tm] = *(const bf16x8*)(As + r * 40 + (lane >> 4) * 8);
    }
#pragma unroll
    for (int tn = 0; tn < 4; ++tn) {
      int r = wn * 64 + tn * 16 + (lane & 15);
      bfr[tn] = *(const bf16x8*)(Bs + r * 40 + (lane >> 4) * 8);
    }
#pragma unroll
    for (int tm = 0; tm < 4; ++tm)
#pragma unroll
      for (int tn = 0; tn < 4; ++tn)
        acc[tm][tn] = __builtin_amdgcn_mfma_f32_16x16x32_bf16(af[tm], bfr[tn], acc[tm][tn], 0, 0, 0);
    __syncthreads();
  }

  // C/D layout: col = lane&15, row = (lane>>4)*4 + i  [m89/m91 verified]
#pragma unroll
  for (int tm = 0; tm < 4; ++tm) {
#pragma unroll
    for (int tn = 0; tn < 4; ++tn) {
      int col = n_base + wn * 64 + tn * 16 + (lane & 15);
#pragma unroll
      for (int i = 0; i < 4; ++i) {
        int row = m_base + wm * 64 + tm * 16 + (lane >> 4) * 4 + i;
        if (row < M)
          Cout[(size_t)row * ldc + col] = __float2bfloat16(acc[tm][tn][i]);
      }
    }
  }
}

// ---------------- LSTM pointwise ----------------
__global__ void lstm_kernel(const bf16* __restrict__ G, float* __restrict__ Cst,
                            bf16* __restrict__ Z, float* __restrict__ out,
                            const float* __restrict__ bias, const float* __restrict__ peep,
                            int t) {
  int idx = blockIdx.x * 256 + threadIdx.x;  // n*128 + c
  int n = idx >> 7, c = idx & 127;
  const bf16* g = G + (size_t)n * 512;
  float Cold = Cst[idx];
  float ai = __bfloat162float(g[c])       + bias[c]       + peep[c] * Cold;
  float af = __bfloat162float(g[128 + c]) + bias[128 + c] + peep[128 + c] * Cold;
  float ac = __bfloat162float(g[256 + c]) + bias[256 + c];
  float ao = __bfloat162float(g[384 + c]) + bias[384 + c];
  float I = 1.f / (1.f + expf(-ai));
  float F = 1.f / (1.f + expf(-af));
  float Tc = tanhf(ac);
  float Cn = F * Cold + I * Tc;
  float O = 1.f / (1.f + expf(-(ao + peep[256 + c] * Cn)));
  float H = O * tanhf(Cn);
  Cst[idx] = Cn;
  Z[(size_t)n * 768 + 384 + c] = __float2bfloat16(H);
  out[((size_t)n * 4 + t) * 128 + c] = H;
}

extern "C" void kernel_launch(void* const* d_in, const int* in_sizes, int n_in,
                              void* d_out, int out_size, void* d_ws, size_t ws_size,
                              hipStream_t stream) {
  const float* X     = (const float*)d_in[0];
  const int*   edges = (const int*)d_in[1];
  const float* Wpool = (const float*)d_in[2];
  const float* convW = (const float*)d_in[3];
  const float* convB = (const float*)d_in[4];
  const float* peep  = (const float*)d_in[5];
  const float* gateB = (const float*)d_in[6];
  float* out = (float*)d_out;

  const int* src = edges;
  const int* dst = edges + EE;

  char* ws = (char*)d_ws;
  size_t off = 0;
  auto alloc = [&](size_t bytes) {
    void* p = ws + off;
    off += (bytes + 255) & ~(size_t)255;
    return p;
  };
  bf16*  WallT   = (bf16*) alloc((size_t)512 * 768 * 2);
  bf16*  WpoolBf = (bf16*) alloc((size_t)128 * 128 * 2);
  float* bias    = (float*)alloc(512 * 4);
  float* dinv    = (float*)alloc(NN * 4);
  int*   counts  = (int*)  alloc(NN * 4);
  int*   rowp    = (int*)  alloc((NN + 1) * 4);
  int*   cursor  = (int*)  alloc(NN * 4);
  uint2* edata   = (uint2*)alloc((size_t)EE * 8);
  float* Cst     = (float*)alloc((size_t)NN * 128 * 4);
  bf16*  Z       = (bf16*) alloc((size_t)NN * 768 * 2);
  bf16*  G       = (bf16*) alloc((size_t)NN * 512 * 2);

  hipMemsetAsync(dinv, 0, NN * 4, stream);
  hipMemsetAsync(counts, 0, NN * 4, stream);
  hipMemsetAsync(Cst, 0, (size_t)NN * 128 * 4, stream);
  hipMemsetAsync(Z, 0, (size_t)NN * 768 * 2, stream);

  prep_kernel<<<1667, 256, 0, stream>>>(convW, convB, gateB, Wpool, WallT, bias, WpoolBf);
  degcount_kernel<<<(EE + 255) / 256, 256, 0, stream>>>(src, dst, dinv, counts);
  dinv_kernel<<<(NN + 255) / 256, 256, 0, stream>>>(dinv);
  scan_kernel<<<1, 1024, 0, stream>>>(counts, rowp, cursor);
  fill_kernel<<<(EE + 255) / 256, 256, 0, stream>>>(src, dst, dinv, cursor, edata);

  dim3 blk(256);
  for (int t = 0; t < TT; ++t) {
    // Xp = X_t @ Wpool^T -> Z[:,0:128]  (Wpool [C][F] is already Bt layout)
    gemm_bt<1><<<dim3(391, 1), blk, 0, stream>>>(X + (size_t)t * NN * 128, 128,
                                                 WpoolBf, 128, Z, 768, NN, 128);
    // PXp (0->128), PH (384->512)
    prop_wide<<<6250, blk, 0, stream>>>(rowp, edata, Z, 0, 128, -1, 384, 512, -1, 1.0f);
    // T2Xp = 2*P*PXp - Xp (128->256, base 0); T2H = 2*P*PH - H (512->640, base 384)
    prop_wide<<<6250, blk, 0, stream>>>(rowp, edata, Z, 128, 256, 0, 512, 640, 384, 2.0f);
    // G[N,512] = Z[N,768] @ W_all
    gemm_bt<0><<<dim3(391, 4), blk, 0, stream>>>(Z, 768, WallT, 768, G, 512, NN, 768);
    // gates + cell update + output
    lstm_kernel<<<(NN * 128) / 256, blk, 0, stream>>>(G, Cst, Z, out, bias, peep, t);
  }
}

// Round 4
// 1228.886 us; speedup vs baseline: 1.7541x; 1.1139x over previous
//
#include <hip/hip_runtime.h>
#include <hip/hip_bf16.h>

#define NN 50000
#define EE 800000
#define TT 4
#define NPAD 50048         // 391*128, padded row count for async-LDS A loads
#define SCAN_NB 49         // ceil(50000/1024)

typedef __hip_bfloat16 bf16;
typedef short bf16x8 __attribute__((ext_vector_type(8)));
typedef float f32x4 __attribute__((ext_vector_type(4)));

__device__ __forceinline__ void async_copy16(const void* g, void* l) {
  __builtin_amdgcn_global_load_lds((const __attribute__((address_space(1))) unsigned int*)g,
                                   (__attribute__((address_space(3))) unsigned int*)l,
                                   16, 0, 0);
}

// ---------------- prep: W_allT [512][768] bf16, fused bias[512] fp32, Wpool bf16 ----------------
__global__ void prep_kernel(const float* __restrict__ convW, const float* __restrict__ convB,
                            const float* __restrict__ gateB, const float* __restrict__ Wpool,
                            bf16* __restrict__ WallT, float* __restrict__ bias,
                            bf16* __restrict__ WpoolBf) {
  int idx = blockIdx.x * 256 + threadIdx.x;
  if (idx < 512 * 768) {
    int nn = idx / 768, k = idx % 768;
    int g = nn >> 7, c = nn & 127;
    int xh = (k >= 384) ? 1 : 0;
    int k2 = k - xh * 384;
    int kch = k2 >> 7, r = k2 & 127;
    WallT[idx] = __float2bfloat16(convW[(((2 * g + xh) * 3 + kch) * 128 + r) * 128 + c]);
  } else if (idx < 512 * 768 + 512) {
    int n2 = idx - 512 * 768;
    int g = n2 >> 7, c = n2 & 127;
    bias[n2] = convB[(2 * g) * 128 + c] + convB[(2 * g + 1) * 128 + c] + gateB[g * 128 + c];
  } else if (idx < 512 * 768 + 512 + 128 * 128) {
    int n3 = idx - (512 * 768 + 512);
    WpoolBf[n3] = __float2bfloat16(Wpool[n3]);
  }
}

// ---------------- graph preprocessing ----------------
__global__ void degcount_kernel(const int* __restrict__ src, const int* __restrict__ dst,
                                float* __restrict__ deg, int* __restrict__ counts) {
  int e = blockIdx.x * 256 + threadIdx.x;
  if (e < EE) {
    atomicAdd(&deg[src[e]], 1.0f);
    atomicAdd(&counts[dst[e]], 1);
  }
}

__global__ void dinv_kernel(float* deg) {
  int n = blockIdx.x * 256 + threadIdx.x;
  if (n < NN) {
    float d = deg[n];
    deg[n] = (d > 0.f) ? rsqrtf(d) : 0.f;
  }
}

// partial sums: block b sums counts[b*1024 .. b*1024+1023]
__global__ void blocksum_kernel(const int* __restrict__ counts, int* __restrict__ bsum) {
  __shared__ int wsum2[4];
  int b = blockIdx.x, tid = threadIdx.x;
  int v = 0;
#pragma unroll
  for (int i = 0; i < 4; ++i) {
    int idx = b * 1024 + tid + i * 256;
    v += (idx < NN) ? counts[idx] : 0;
  }
#pragma unroll
  for (int off = 32; off; off >>= 1) v += __shfl_down(v, off);
  if ((tid & 63) == 0) wsum2[tid >> 6] = v;
  __syncthreads();
  if (tid == 0) bsum[b] = wsum2[0] + wsum2[1] + wsum2[2] + wsum2[3];
}

// full scan: each block re-reads the 49 block sums, scans its own 1024 chunk
__global__ void scan2_kernel(const int* __restrict__ counts, const int* __restrict__ bsum,
                             int* __restrict__ row_ptr, int* __restrict__ cursor) {
  __shared__ int wsum[16];
  int b = blockIdx.x, tid = threadIdx.x;
  int lane = tid & 63, wv = tid >> 6;
  int boff = 0, total = 0;
  for (int i = 0; i < SCAN_NB; ++i) {
    int s = bsum[i];
    if (i < b) boff += s;
    total += s;
  }
  int idx = b * 1024 + tid;
  int v = (idx < NN) ? counts[idx] : 0;
  int sc = v;
#pragma unroll
  for (int off = 1; off < 64; off <<= 1) {
    int t = __shfl_up(sc, off);
    if (lane >= off) sc += t;
  }
  if (lane == 63) wsum[wv] = sc;
  __syncthreads();
  if (wv == 0) {
    int w = (lane < 16) ? wsum[lane] : 0;
#pragma unroll
    for (int off = 1; off < 16; off <<= 1) {
      int t = __shfl_up(w, off);
      if (lane >= off) w += t;
    }
    if (lane < 16) wsum[lane] = w;
  }
  __syncthreads();
  int excl = boff + sc - v + (wv ? wsum[wv - 1] : 0);
  if (idx < NN) { row_ptr[idx] = excl; cursor[idx] = excl; }
  if (b == 0 && tid == 0) row_ptr[NN] = total;
}

// pack (src, weight) per edge into uint2
__global__ void fill_kernel(const int* __restrict__ src, const int* __restrict__ dst,
                            const float* __restrict__ dinv, int* __restrict__ cursor,
                            uint2* __restrict__ edata) {
  int e = blockIdx.x * 256 + threadIdx.x;
  if (e < EE) {
    int s = src[e], d = dst[e];
    float w = -(dinv[s] * dinv[d]);
    int pos = atomicAdd(&cursor[d], 1);
    uint2 v;
    v.x = (unsigned)s;
    v.y = __float_as_uint(w);
    edata[pos] = v;
  }
}

// zero the H window Z[:,384:512)
__global__ void zeroH_kernel(bf16* __restrict__ Z) {
  int i = blockIdx.x * 256 + threadIdx.x;
  if (i < NN * 16) {
    int n = i >> 4, c = i & 15;
    *(uint4*)(Z + (size_t)n * 768 + 384 + c * 8) = make_uint4(0u, 0u, 0u, 0u);
  }
}

// ---------------- prop: out = scale * (P @ in) - base ----------------
__device__ __forceinline__ void accum8(float* acc, uint4 z, float w) {
  float f0 = __uint_as_float(z.x << 16);
  float f1 = __uint_as_float(z.x & 0xffff0000u);
  float f2 = __uint_as_float(z.y << 16);
  float f3 = __uint_as_float(z.y & 0xffff0000u);
  float f4 = __uint_as_float(z.z << 16);
  float f5 = __uint_as_float(z.z & 0xffff0000u);
  float f6 = __uint_as_float(z.w << 16);
  float f7 = __uint_as_float(z.w & 0xffff0000u);
  acc[0] = fmaf(w, f0, acc[0]);
  acc[1] = fmaf(w, f1, acc[1]);
  acc[2] = fmaf(w, f2, acc[2]);
  acc[3] = fmaf(w, f3, acc[3]);
  acc[4] = fmaf(w, f4, acc[4]);
  acc[5] = fmaf(w, f5, acc[5]);
  acc[6] = fmaf(w, f6, acc[6]);
  acc[7] = fmaf(w, f7, acc[7]);
}

__global__ __launch_bounds__(256) void prop_wide(const int* __restrict__ row_ptr,
                                                 const uint2* __restrict__ edata,
                                                 bf16* __restrict__ Z,
                                                 int in_offA, int out_offA, int baseA,
                                                 int in_offB, int out_offB, int baseB,
                                                 float scale) {
  int tid = threadIdx.x;
  int grp = tid >> 7;
  int sub = tid & 127;
  int node = blockIdx.x * 8 + (sub >> 4);
  int lane8 = sub & 15;
  int in_off  = grp ? in_offB  : in_offA;
  int out_off = grp ? out_offB : out_offA;
  int base    = grp ? baseB    : baseA;
  int e0 = row_ptr[node], e1 = row_ptr[node + 1];
  float acc[8] = {0.f, 0.f, 0.f, 0.f, 0.f, 0.f, 0.f, 0.f};
  const bf16* zin = Z + in_off + lane8 * 8;
  int e = e0;
  for (; e + 4 <= e1; e += 4) {
    uint2 d0 = edata[e];
    uint2 d1 = edata[e + 1];
    uint2 d2 = edata[e + 2];
    uint2 d3 = edata[e + 3];
    uint4 z0 = *(const uint4*)(zin + (size_t)d0.x * 768);
    uint4 z1 = *(const uint4*)(zin + (size_t)d1.x * 768);
    uint4 z2 = *(const uint4*)(zin + (size_t)d2.x * 768);
    uint4 z3 = *(const uint4*)(zin + (size_t)d3.x * 768);
    accum8(acc, z0, __uint_as_float(d0.y));
    accum8(acc, z1, __uint_as_float(d1.y));
    accum8(acc, z2, __uint_as_float(d2.y));
    accum8(acc, z3, __uint_as_float(d3.y));
  }
  for (; e < e1; ++e) {
    uint2 d = edata[e];
    uint4 z = *(const uint4*)(zin + (size_t)d.x * 768);
    accum8(acc, z, __uint_as_float(d.y));
  }
  float bv[8] = {0.f, 0.f, 0.f, 0.f, 0.f, 0.f, 0.f, 0.f};
  if (base >= 0) {
    uint4 b = *(const uint4*)(Z + (size_t)node * 768 + base + lane8 * 8);
    bv[0] = __uint_as_float(b.x << 16);
    bv[1] = __uint_as_float(b.x & 0xffff0000u);
    bv[2] = __uint_as_float(b.y << 16);
    bv[3] = __uint_as_float(b.y & 0xffff0000u);
    bv[4] = __uint_as_float(b.z << 16);
    bv[5] = __uint_as_float(b.z & 0xffff0000u);
    bv[6] = __uint_as_float(b.w << 16);
    bv[7] = __uint_as_float(b.w & 0xffff0000u);
  }
  union {
    bf16 h[8];
    uint4 v;
  } o;
#pragma unroll
  for (int j = 0; j < 8; ++j)
    o.h[j] = __float2bfloat16(fmaf(scale, acc[j], -bv[j]));
  *(uint4*)(Z + (size_t)node * 768 + out_off + lane8 * 8) = o.v;
}

// ---------------- GEMM: C[M,Nc] = A[M,K] @ Bt[Nc,K]^T, fp32 acc ----------------
// Flat LDS tiles (128 rows x 32 bf16 = 64B/row), XOR-swizzled 16B chunks:
// element chunk (row r, kseg s) lives at chunk index r*4 + (s ^ ((r>>1)&3)).
// -> global_load_lds wave-uniform-base+lane*16 writes land correctly, and the
//    b128 fragment reads hit each 16B bank-quad exactly 2x (2-way = free, m136).
// A_FP32=1: manual fp32->bf16 convert staging for A (with M guard); else async.
// A rows up to blockIdx bound must be allocated (NPAD) when A_FP32=0.
template <int A_FP32>
__global__ __launch_bounds__(256) void gemm_bt(const void* __restrict__ Ain, int lda,
                                               const bf16* __restrict__ Bt, int ldbt,
                                               bf16* __restrict__ Cout, int ldc,
                                               int M, int K) {
  __shared__ __align__(16) bf16 As[128 * 32];
  __shared__ __align__(16) bf16 Bs[128 * 32];
  const int tid = threadIdx.x;
  const int lane = tid & 63, wid = tid >> 6;
  const int wm = wid >> 1, wn = wid & 1;
  const int m_base = blockIdx.x * 128;
  const int n_base = blockIdx.y * 128;
  f32x4 acc[4][4] = {};

  // staging chunks c0 = tid, c1 = tid + 256; r = c>>2, p = c&3, s = p ^ ((r>>1)&3)
  const int r0 = tid >> 2, p = tid & 3;
  const int r1 = r0 + 64;
  const int s0 = p ^ ((r0 >> 1) & 3);
  const int s1 = p ^ ((r1 >> 1) & 3);

  const bf16* Ag0 = (const bf16*)Ain + (size_t)(m_base + r0) * lda + s0 * 8;
  const bf16* Ag1 = (const bf16*)Ain + (size_t)(m_base + r1) * lda + s1 * 8;
  const float* Af0 = (const float*)Ain + (size_t)(m_base + r0) * lda + s0 * 8;
  const float* Af1 = (const float*)Ain + (size_t)(m_base + r1) * lda + s1 * 8;
  const bf16* Bg0 = Bt + (size_t)(n_base + r0) * ldbt + s0 * 8;
  const bf16* Bg1 = Bt + (size_t)(n_base + r1) * ldbt + s1 * 8;

  // wave-uniform LDS bases (elem offsets): chunk base (it*256 + wid*64) * 8
  bf16* ldsA0 = As + wid * 512;
  bf16* ldsA1 = As + 2048 + wid * 512;
  bf16* ldsB0 = Bs + wid * 512;
  bf16* ldsB1 = Bs + 2048 + wid * 512;

  // fragment LDS elem offsets, fixed per lane
  int offA[4], offB[4];
  const int sq = lane >> 4;
#pragma unroll
  for (int tm = 0; tm < 4; ++tm) {
    int r = wm * 64 + tm * 16 + (lane & 15);
    offA[tm] = r * 32 + (sq ^ ((r >> 1) & 3)) * 8;
  }
#pragma unroll
  for (int tn = 0; tn < 4; ++tn) {
    int r = wn * 64 + tn * 16 + (lane & 15);
    offB[tn] = r * 32 + (sq ^ ((r >> 1) & 3)) * 8;
  }

  for (int k0 = 0; k0 < K; k0 += 32) {
    if (A_FP32) {
      {
        float4 f0 = make_float4(0.f, 0.f, 0.f, 0.f), f1 = f0;
        if (m_base + r0 < M) { f0 = *(const float4*)Af0; f1 = *(const float4*)(Af0 + 4); }
        bf16 tmp[8];
        tmp[0] = __float2bfloat16(f0.x); tmp[1] = __float2bfloat16(f0.y);
        tmp[2] = __float2bfloat16(f0.z); tmp[3] = __float2bfloat16(f0.w);
        tmp[4] = __float2bfloat16(f1.x); tmp[5] = __float2bfloat16(f1.y);
        tmp[6] = __float2bfloat16(f1.z); tmp[7] = __float2bfloat16(f1.w);
        *(uint4*)(As + tid * 8) = *(const uint4*)tmp;
      }
      {
        float4 f0 = make_float4(0.f, 0.f, 0.f, 0.f), f1 = f0;
        if (m_base + r1 < M) { f0 = *(const float4*)Af1; f1 = *(const float4*)(Af1 + 4); }
        bf16 tmp[8];
        tmp[0] = __float2bfloat16(f0.x); tmp[1] = __float2bfloat16(f0.y);
        tmp[2] = __float2bfloat16(f0.z); tmp[3] = __float2bfloat16(f0.w);
        tmp[4] = __float2bfloat16(f1.x); tmp[5] = __float2bfloat16(f1.y);
        tmp[6] = __float2bfloat16(f1.z); tmp[7] = __float2bfloat16(f1.w);
        *(uint4*)(As + (tid + 256) * 8) = *(const uint4*)tmp;
      }
      Af0 += 32; Af1 += 32;
    } else {
      async_copy16(Ag0, ldsA0);
      async_copy16(Ag1, ldsA1);
      Ag0 += 32; Ag1 += 32;
    }
    async_copy16(Bg0, ldsB0);
    async_copy16(Bg1, ldsB1);
    Bg0 += 32; Bg1 += 32;
    __syncthreads();

    bf16x8 af[4], bfr[4];
#pragma unroll
    for (int tm = 0; tm < 4; ++tm) af[tm] = *(const bf16x8*)(As + offA[tm]);
#pragma unroll
    for (int tn = 0; tn < 4; ++tn) bfr[tn] = *(const bf16x8*)(Bs + offB[tn]);
#pragma unroll
    for (int tm = 0; tm < 4; ++tm)
#pragma unroll
      for (int tn = 0; tn < 4; ++tn)
        acc[tm][tn] = __builtin_amdgcn_mfma_f32_16x16x32_bf16(af[tm], bfr[tn], acc[tm][tn], 0, 0, 0);
    __syncthreads();
  }

  // C/D layout: col = lane&15, row = (lane>>4)*4 + i  [m89/m91 verified]
#pragma unroll
  for (int tm = 0; tm < 4; ++tm) {
#pragma unroll
    for (int tn = 0; tn < 4; ++tn) {
      int col = n_base + wn * 64 + tn * 16 + (lane & 15);
#pragma unroll
      for (int i = 0; i < 4; ++i) {
        int row = m_base + wm * 64 + tm * 16 + (lane >> 4) * 4 + i;
        if (row < M)
          Cout[(size_t)row * ldc + col] = __float2bfloat16(acc[tm][tn][i]);
      }
    }
  }
}

// ---------------- LSTM pointwise ----------------
__global__ void lstm_kernel(const bf16* __restrict__ G, float* __restrict__ Cst,
                            bf16* __restrict__ Z, float* __restrict__ out,
                            const float* __restrict__ bias, const float* __restrict__ peep,
                            int t) {
  int idx = blockIdx.x * 256 + threadIdx.x;  // n*128 + c
  int n = idx >> 7, c = idx & 127;
  const bf16* g = G + (size_t)n * 512;
  float Cold = Cst[idx];
  float ai = __bfloat162float(g[c])       + bias[c]       + peep[c] * Cold;
  float af = __bfloat162float(g[128 + c]) + bias[128 + c] + peep[128 + c] * Cold;
  float ac = __bfloat162float(g[256 + c]) + bias[256 + c];
  float ao = __bfloat162float(g[384 + c]) + bias[384 + c];
  float I = 1.f / (1.f + expf(-ai));
  float F = 1.f / (1.f + expf(-af));
  float Tc = tanhf(ac);
  float Cn = F * Cold + I * Tc;
  float O = 1.f / (1.f + expf(-(ao + peep[256 + c] * Cn)));
  float H = O * tanhf(Cn);
  Cst[idx] = Cn;
  Z[(size_t)n * 768 + 384 + c] = __float2bfloat16(H);
  out[((size_t)n * 4 + t) * 128 + c] = H;
}

extern "C" void kernel_launch(void* const* d_in, const int* in_sizes, int n_in,
                              void* d_out, int out_size, void* d_ws, size_t ws_size,
                              hipStream_t stream) {
  const float* X     = (const float*)d_in[0];
  const int*   edges = (const int*)d_in[1];
  const float* Wpool = (const float*)d_in[2];
  const float* convW = (const float*)d_in[3];
  const float* convB = (const float*)d_in[4];
  const float* peep  = (const float*)d_in[5];
  const float* gateB = (const float*)d_in[6];
  float* out = (float*)d_out;

  const int* src = edges;
  const int* dst = edges + EE;

  char* ws = (char*)d_ws;
  size_t off = 0;
  auto alloc = [&](size_t bytes) {
    void* p = ws + off;
    off += (bytes + 255) & ~(size_t)255;
    return p;
  };
  bf16*  WallT   = (bf16*) alloc((size_t)512 * 768 * 2);
  bf16*  WpoolBf = (bf16*) alloc((size_t)128 * 128 * 2);
  float* bias    = (float*)alloc(512 * 4);
  float* dinv    = (float*)alloc(NN * 4);
  int*   counts  = (int*)  alloc(NN * 4);
  int*   rowp    = (int*)  alloc((NN + 1) * 4);
  int*   cursor  = (int*)  alloc(NN * 4);
  int*   bsum    = (int*)  alloc(SCAN_NB * 4);
  uint2* edata   = (uint2*)alloc((size_t)EE * 8);
  float* Cst     = (float*)alloc((size_t)NN * 128 * 4);
  bf16*  Z       = (bf16*) alloc((size_t)NPAD * 768 * 2);
  bf16*  G       = (bf16*) alloc((size_t)NN * 512 * 2);

  hipMemsetAsync(dinv, 0, NN * 4, stream);
  hipMemsetAsync(counts, 0, NN * 4, stream);
  hipMemsetAsync(Cst, 0, (size_t)NN * 128 * 4, stream);

  prep_kernel<<<1667, 256, 0, stream>>>(convW, convB, gateB, Wpool, WallT, bias, WpoolBf);
  degcount_kernel<<<(EE + 255) / 256, 256, 0, stream>>>(src, dst, dinv, counts);
  dinv_kernel<<<(NN + 255) / 256, 256, 0, stream>>>(dinv);
  blocksum_kernel<<<SCAN_NB, 256, 0, stream>>>(counts, bsum);
  scan2_kernel<<<SCAN_NB, 1024, 0, stream>>>(counts, bsum, rowp, cursor);
  fill_kernel<<<(EE + 255) / 256, 256, 0, stream>>>(src, dst, dinv, cursor, edata);
  zeroH_kernel<<<(NN * 16 + 255) / 256, 256, 0, stream>>>(Z);

  dim3 blk(256);
  for (int t = 0; t < TT; ++t) {
    // Xp = X_t @ Wpool^T -> Z[:,0:128]
    gemm_bt<1><<<dim3(391, 1), blk, 0, stream>>>(X + (size_t)t * NN * 128, 128,
                                                 WpoolBf, 128, Z, 768, NN, 128);
    // PXp (0->128), PH (384->512)
    prop_wide<<<6250, blk, 0, stream>>>(rowp, edata, Z, 0, 128, -1, 384, 512, -1, 1.0f);
    // T2Xp = 2*P*PXp - Xp (128->256, base 0); T2H = 2*P*PH - H (512->640, base 384)
    prop_wide<<<6250, blk, 0, stream>>>(rowp, edata, Z, 128, 256, 0, 512, 640, 384, 2.0f);
    // G[N,512] = Z[N,768] @ W_all
    gemm_bt<0><<<dim3(391, 4), blk, 0, stream>>>(Z, 768, WallT, 768, G, 512, NN, 768);
    // gates + cell update + output
    lstm_kernel<<<(NN * 128) / 256, blk, 0, stream>>>(G, Cst, Z, out, bias, peep, t);
  }
}